// Round 12
// baseline (224.205 us; speedup 1.0000x reference)
//
#include <hip/hip_runtime.h>
#include <hip/hip_bf16.h>

// DotProductAttention: B=16, LQ=LKV=2048, D=64, fp32 in/out, per-batch valid_lens.
// Flash-style online softmax; hi/lo bf16 split MFMA (near-fp32 accuracy).
// R7 counters: Occ 28% (grid=512=2/CU exactly, no backfill; tail-dominated),
// MfmaUtil 16.5, VALU 33, conflicts 3.1M. R8: QBLK=128 (8 waves share one 32KB
// stage), KV split grid.z=4 -> 1024 blocks, <=64 VGPR -> 4 blocks/CU = 32
// waves/CU + backfill; partials to d_ws + combine kernel. Fallback = R7 kernel.
// (R11: fourth resubmission after broker timeouts; re-audited, unchanged.)

#define NB   16
#define LQS  2048
#define LKVS 2048
#define DH   64
#define KVB  64
#define NZ   4
#define TPZ  8          // KV tiles per z-part = 2048/64/4

typedef short bf16x8 __attribute__((ext_vector_type(8)));
typedef float f32x4  __attribute__((ext_vector_type(4)));

__device__ __forceinline__ unsigned short f2bf(float x) {
    return __builtin_bit_cast(unsigned short, __float2bfloat16(x));
}
__device__ __forceinline__ float bf2f(unsigned short h) {
    return __uint_as_float(((unsigned int)h) << 16);
}
__device__ __forceinline__ int vswz(int d) {          // V-tile swizzle (bits 3..5)
    return (((d & 7) ^ (d >> 3)) << 3);
}

// ===================== split main kernel: grid (16, NB, NZ), 512 thr =====================
__global__ __launch_bounds__(512, 8) void attn_fa_split(
    const float* __restrict__ Qg, const float* __restrict__ Kg,
    const float* __restrict__ Vg, const int* __restrict__ vlg,
    float* __restrict__ Po, float* __restrict__ Pm, float* __restrict__ Pl)
{
    // K [key][d] bf16 rows, swizzle ^((key&7)<<3) (8-ushort granularity).
    // V transposed [d][pos(key)], pos(t)=(t&~31)|(((t>>2)&3)<<3)|(((t>>4)&1)<<2)|(t&3),
    // swizzle vswz(d); PV b128 read at position 32s+8g+i = key 32s+4g+(i&3)+16(i>>2).
    __shared__ __align__(16) unsigned short sKhi[KVB * DH];
    __shared__ __align__(16) unsigned short sKlo[KVB * DH];
    __shared__ __align__(16) unsigned short sVhi[DH * KVB];
    __shared__ __align__(16) unsigned short sVlo[DH * KVB];

    const int b    = blockIdx.y;
    const int z    = blockIdx.z;
    const int q0   = blockIdx.x * 128;
    const int tid  = threadIdx.x;
    const int w8   = tid >> 6;        // wave 0..7, owns 16 q rows
    const int lane = tid & 63;
    const int lr   = lane & 15;       // q column
    const int lg   = lane >> 4;       // k-group 0..3
    const int n_valid = vlg[b];

    const int nsteps  = (n_valid + KVB - 1) / KVB;
    const int t_begin = z * TPZ;
    const int t_end   = min(nsteps, t_begin + TPZ);
    const int ntiles  = max(0, t_end - t_begin);

    // staging geometry
    const int kb2 = ((tid >> 4) & 31) * 2;                 // V: 2-key base (coalesced rows)
    const int db  = (tid & 15) * 4;                        // V: 4-d base
    const int pos2 = (kb2 & 32) | (((kb2 >> 2) & 3) << 3) | (((kb2 >> 4) & 1) << 2) | (kb2 & 3);

    // ---- Q fragments (B-operand; col = q = lr): scale by 1/8 (exact) then split ----
    bf16x8 qhi[2], qlo[2];
    {
        const float* qp = Qg + ((size_t)b * LQS + q0 + w8 * 16 + lr) * DH;
        #pragma unroll
        for (int s = 0; s < 2; ++s) {
            const float4 a = *(const float4*)(qp + s * 32 + lg * 8);
            const float4 c = *(const float4*)(qp + s * 32 + lg * 8 + 4);
            const float vv[8] = {a.x, a.y, a.z, a.w, c.x, c.y, c.z, c.w};
            #pragma unroll
            for (int i = 0; i < 8; ++i) {
                const float x = vv[i] * 0.125f;
                const unsigned short h = f2bf(x);
                qhi[s][i] = (short)h;
                qlo[s][i] = (short)f2bf(x - bf2f(h));
            }
        }
    }

    f32x4 o[4];
    #pragma unroll
    for (int nt = 0; nt < 4; ++nt) { o[nt][0]=0.f; o[nt][1]=0.f; o[nt][2]=0.f; o[nt][3]=0.f; }
    float m_q = -__builtin_inff();
    float l_q = 0.f;

    // ---- prefetch registers (T14): current tile's raw K/V ----
    float4 kq[2], vr[2];
    if (ntiles > 0) {
        const float* kp = Kg + ((size_t)b * LKVS + t_begin * KVB) * DH;
        const float* vp = Vg + ((size_t)b * LKVS + t_begin * KVB) * DH;
        #pragma unroll
        for (int it = 0; it < 2; ++it) {
            const int idx = tid + it * 512;
            kq[it] = *(const float4*)(kp + (idx >> 4) * DH + (idx & 15) * 4);
        }
        #pragma unroll
        for (int j = 0; j < 2; ++j)
            vr[j] = *(const float4*)(vp + (kb2 + j) * DH + db);
    }

    for (int stl = 0; stl < ntiles; ++stl) {
        const int kv0 = (t_begin + stl) * KVB;
        __syncthreads();   // previous tile fully consumed before overwrite
        // ---- convert prefetched regs -> LDS ----
        #pragma unroll
        for (int it = 0; it < 2; ++it) {
            const int idx = tid + it * 512;
            const int key = idx >> 4, f4 = idx & 15;
            const float ka[4] = {kq[it].x, kq[it].y, kq[it].z, kq[it].w};
            unsigned short kh[4], kl[4];
            #pragma unroll
            for (int i = 0; i < 4; ++i) {
                kh[i] = f2bf(ka[i]);
                kl[i] = f2bf(ka[i] - bf2f(kh[i]));
            }
            const int kb_ = key * 64 + (((f4 * 4) & ~7) ^ ((key & 7) << 3)) + (f4 & 1) * 4;
            *(ushort4*)(&sKhi[kb_]) = make_ushort4(kh[0], kh[1], kh[2], kh[3]);
            *(ushort4*)(&sKlo[kb_]) = make_ushort4(kl[0], kl[1], kl[2], kl[3]);
        }
        #pragma unroll
        for (int i = 0; i < 4; ++i) {
            const int d = db + i;
            const float f0 = (&vr[0].x)[i], f1 = (&vr[1].x)[i];
            const unsigned short h0 = f2bf(f0), h1 = f2bf(f1);
            const int vi = d * 64 + (pos2 ^ vswz(d));
            *(ushort2*)(&sVhi[vi]) = make_ushort2(h0, h1);
            *(ushort2*)(&sVlo[vi]) = make_ushort2(f2bf(f0 - bf2f(h0)), f2bf(f1 - bf2f(h1)));
        }
        __syncthreads();

        // ---- issue next tile's loads (latency hides under compute below) ----
        if (stl + 1 < ntiles) {
            const float* kp = Kg + ((size_t)b * LKVS + (kv0 + KVB)) * DH;
            const float* vp = Vg + ((size_t)b * LKVS + (kv0 + KVB)) * DH;
            #pragma unroll
            for (int it = 0; it < 2; ++it) {
                const int idx = tid + it * 512;
                kq[it] = *(const float4*)(kp + (idx >> 4) * DH + (idx & 15) * 4);
            }
            #pragma unroll
            for (int j = 0; j < 2; ++j)
                vr[j] = *(const float4*)(vp + (kb2 + j) * DH + db);
        }

        // ---- QK^T swapped: P[key, q] = mfma(K, Q) ----
        float p_[4][4];
        __builtin_amdgcn_s_setprio(1);
        #pragma unroll
        for (int kt = 0; kt < 4; ++kt) {
            f32x4 acc = {0.f, 0.f, 0.f, 0.f};
            const int key = kt * 16 + lr;
            #pragma unroll
            for (int s = 0; s < 2; ++s) {
                const int ki = key * 64 + ((s * 32 + lg * 8) ^ ((key & 7) << 3));
                const bf16x8 khi = *(const bf16x8*)(&sKhi[ki]);
                const bf16x8 klo = *(const bf16x8*)(&sKlo[ki]);
                acc = __builtin_amdgcn_mfma_f32_16x16x32_bf16(khi, qhi[s], acc, 0, 0, 0);
                acc = __builtin_amdgcn_mfma_f32_16x16x32_bf16(khi, qlo[s], acc, 0, 0, 0);
                acc = __builtin_amdgcn_mfma_f32_16x16x32_bf16(klo, qhi[s], acc, 0, 0, 0);
            }
            #pragma unroll
            for (int r = 0; r < 4; ++r) p_[kt][r] = acc[r];
        }
        __builtin_amdgcn_s_setprio(0);

        // ---- mask (partial last global tile): key = kv0 + 16*kt + 4*lg + r ----
        if (kv0 + KVB > n_valid) {
            #pragma unroll
            for (int kt = 0; kt < 4; ++kt) {
                #pragma unroll
                for (int r = 0; r < 4; ++r) {
                    if (kv0 + kt * 16 + lg * 4 + r >= n_valid) p_[kt][r] = -1000000.0f;
                }
            }
        }

        // ---- in-register online softmax for q = lr ----
        float tm = p_[0][0];
        #pragma unroll
        for (int kt = 0; kt < 4; ++kt) {
            #pragma unroll
            for (int r = 0; r < 4; ++r) tm = fmaxf(tm, p_[kt][r]);
        }
        tm = fmaxf(tm, __shfl_xor(tm, 16));
        tm = fmaxf(tm, __shfl_xor(tm, 32));
        const float mn = fmaxf(m_q, tm);
        const float sc = __expf(m_q - mn);
        float rs = 0.f;
        #pragma unroll
        for (int kt = 0; kt < 4; ++kt) {
            #pragma unroll
            for (int r = 0; r < 4; ++r) {
                p_[kt][r] = __expf(p_[kt][r] - mn);
                rs += p_[kt][r];
            }
        }
        rs += __shfl_xor(rs, 16);
        rs += __shfl_xor(rs, 32);
        l_q = l_q * sc + rs;
        m_q = mn;
        #pragma unroll
        for (int r = 0; r < 4; ++r) {
            const float scr = __shfl(sc, lg * 4 + r);
            #pragma unroll
            for (int nt = 0; nt < 4; ++nt) o[nt][r] *= scr;
        }

        // ---- PV: O += P * V; P direct from regs ----
        #pragma unroll
        for (int s = 0; s < 2; ++s) {
            bf16x8 phi, plo;
            #pragma unroll
            for (int i = 0; i < 8; ++i) {
                const float v = p_[2 * s + (i >> 2)][i & 3];
                const unsigned short h = f2bf(v);
                phi[i] = (short)h;
                plo[i] = (short)f2bf(v - bf2f(h));
            }
            const int cb = s * 32 + lg * 8;
            __builtin_amdgcn_s_setprio(1);
            #pragma unroll
            for (int nt = 0; nt < 4; ++nt) {
                const int d  = nt * 16 + lr;
                const int vi = d * 64 + (cb ^ vswz(d));
                const bf16x8 vhi = *(const bf16x8*)(&sVhi[vi]);
                const bf16x8 vlo = *(const bf16x8*)(&sVlo[vi]);
                o[nt] = __builtin_amdgcn_mfma_f32_16x16x32_bf16(phi, vhi, o[nt], 0, 0, 0);
                o[nt] = __builtin_amdgcn_mfma_f32_16x16x32_bf16(plo, vhi, o[nt], 0, 0, 0);
                o[nt] = __builtin_amdgcn_mfma_f32_16x16x32_bf16(phi, vlo, o[nt], 0, 0, 0);
            }
            __builtin_amdgcn_s_setprio(0);
        }
    }

    // ---- write partials (unnormalized O, m, l); ntiles==0 -> zeros/-inf/0 ----
    const size_t rb = (size_t)(z * NB + b) * LQS + q0 + w8 * 16;
    #pragma unroll
    for (int r = 0; r < 4; ++r) {
        const int row = lg * 4 + r;
        float* op = Po + (rb + row) * DH + lr;
        #pragma unroll
        for (int nt = 0; nt < 4; ++nt) op[nt * 16] = o[nt][r];
    }
    if (lg == 0) {
        Pm[rb + lr] = m_q;
        Pl[rb + lr] = l_q;
    }
}

// ===================== combine kernel: 4 partials -> O =====================
__global__ __launch_bounds__(256) void attn_combine(
    const float* __restrict__ Po, const float* __restrict__ Pm,
    const float* __restrict__ Pl, float* __restrict__ Og)
{
    const int e   = blockIdx.x * 256 + threadIdx.x;   // [0, NB*LQS*DH)
    const int row = e >> 6;                           // b*LQS + q (wave-uniform)
    float mz[NZ], lz[NZ];
    float m = -__builtin_inff();
    #pragma unroll
    for (int zi = 0; zi < NZ; ++zi) {
        mz[zi] = Pm[zi * (NB * LQS) + row];
        lz[zi] = Pl[zi * (NB * LQS) + row];
        m = fmaxf(m, mz[zi]);
    }
    float num = 0.f, den = 0.f;
    #pragma unroll
    for (int zi = 0; zi < NZ; ++zi) {
        if (lz[zi] > 0.f) {                           // guards exp(-inf - -inf)
            const float a = __expf(mz[zi] - m);
            num += a * Po[(size_t)zi * (NB * LQS * DH) + e];
            den += a * lz[zi];
        }
    }
    Og[e] = num / den;                                // den >= l(z=0) > 0
}

// ===================== fallback: R7 kernel (proven), grid (32,NB), 512 thr =====================
__global__ __launch_bounds__(512, 4) void attn_fa(
    const float* __restrict__ Qg, const float* __restrict__ Kg,
    const float* __restrict__ Vg, const int* __restrict__ vlg,
    float* __restrict__ Og)
{
    __shared__ __align__(16) unsigned short sMem[2][4 * KVB * DH];   // 64 KB

    const int b    = blockIdx.y;
    const int q0   = blockIdx.x * 64;
    const int tid  = threadIdx.x;
    const int wg   = tid >> 8;
    const int gtid = tid & 255;
    const int w4   = (tid >> 6) & 3;
    const int lane = tid & 63;
    const int lr   = lane & 15;
    const int lg   = lane >> 4;
    const int n_valid = vlg[b];

    unsigned short* sKhi = &sMem[wg][0];
    unsigned short* sKlo = &sMem[wg][4096];
    unsigned short* sVhi = &sMem[wg][8192];
    unsigned short* sVlo = &sMem[wg][12288];

    const int kb = (gtid >> 4) * 4;
    const int db = (gtid & 15) * 4;
    const int pb = (kb & ~31) | (((kb >> 2) & 3) << 3) | (((kb >> 4) & 1) << 2);

    bf16x8 qhi[2], qlo[2];
    {
        const float* qp = Qg + ((size_t)b * LQS + q0 + w4 * 16 + lr) * DH;
        #pragma unroll
        for (int s = 0; s < 2; ++s) {
            const float4 a = *(const float4*)(qp + s * 32 + lg * 8);
            const float4 c = *(const float4*)(qp + s * 32 + lg * 8 + 4);
            const float vv[8] = {a.x, a.y, a.z, a.w, c.x, c.y, c.z, c.w};
            #pragma unroll
            for (int i = 0; i < 8; ++i) {
                const float x = vv[i] * 0.125f;
                const unsigned short h = f2bf(x);
                qhi[s][i] = (short)h;
                qlo[s][i] = (short)f2bf(x - bf2f(h));
            }
        }
    }

    f32x4 o[4];
    #pragma unroll
    for (int nt = 0; nt < 4; ++nt) { o[nt][0]=0.f; o[nt][1]=0.f; o[nt][2]=0.f; o[nt][3]=0.f; }
    float m_q = -__builtin_inff();
    float l_q = 0.f;

    const int nsteps = (n_valid + KVB - 1) / KVB;
    const int rounds = (nsteps + 1) >> 1;

    float4 kq[4], vr[4];
    if (wg < nsteps) {
        const float* kp = Kg + ((size_t)b * LKVS + wg * KVB) * DH;
        const float* vp = Vg + ((size_t)b * LKVS + wg * KVB) * DH;
        #pragma unroll
        for (int it = 0; it < 4; ++it) {
            const int idx = gtid + it * 256;
            kq[it] = *(const float4*)(kp + (idx >> 4) * DH + (idx & 15) * 4);
        }
        #pragma unroll
        for (int j = 0; j < 4; ++j)
            vr[j] = *(const float4*)(vp + (kb + j) * DH + db);
    }

    for (int jt = 0; jt < rounds; ++jt) {
        const int st  = 2 * jt + wg;
        const bool act = (st < nsteps);
        const int kv0 = st * KVB;
        __syncthreads();
        if (act) {
            #pragma unroll
            for (int it = 0; it < 4; ++it) {
                const int idx = gtid + it * 256;
                const int key = idx >> 4, f4 = idx & 15;
                const float ka[4] = {kq[it].x, kq[it].y, kq[it].z, kq[it].w};
                unsigned short kh[4], kl[4];
                #pragma unroll
                for (int i = 0; i < 4; ++i) {
                    kh[i] = f2bf(ka[i]);
                    kl[i] = f2bf(ka[i] - bf2f(kh[i]));
                }
                const int kb_ = key * 64 + (((f4 * 4) & ~7) ^ ((key & 7) << 3)) + (f4 & 1) * 4;
                *(ushort4*)(&sKhi[kb_]) = make_ushort4(kh[0], kh[1], kh[2], kh[3]);
                *(ushort4*)(&sKlo[kb_]) = make_ushort4(kl[0], kl[1], kl[2], kl[3]);
            }
            #pragma unroll
            for (int i = 0; i < 4; ++i) {
                const int d = db + i;
                const float f0 = (&vr[0].x)[i], f1 = (&vr[1].x)[i];
                const float f2_ = (&vr[2].x)[i], f3 = (&vr[3].x)[i];
                const unsigned short h0 = f2bf(f0), h1 = f2bf(f1);
                const unsigned short h2 = f2bf(f2_), h3 = f2bf(f3);
                const int vi = d * 64 + (pb ^ vswz(d));
                *(ushort4*)(&sVhi[vi]) = make_ushort4(h0, h1, h2, h3);
                *(ushort4*)(&sVlo[vi]) = make_ushort4(
                    f2bf(f0 - bf2f(h0)), f2bf(f1 - bf2f(h1)),
                    f2bf(f2_ - bf2f(h2)), f2bf(f3 - bf2f(h3)));
            }
        }
        __syncthreads();

        {
            const int stn = st + 2;
            if (stn < nsteps) {
                const float* kp = Kg + ((size_t)b * LKVS + stn * KVB) * DH;
                const float* vp = Vg + ((size_t)b * LKVS + stn * KVB) * DH;
                #pragma unroll
                for (int it = 0; it < 4; ++it) {
                    const int idx = gtid + it * 256;
                    kq[it] = *(const float4*)(kp + (idx >> 4) * DH + (idx & 15) * 4);
                }
                #pragma unroll
                for (int j = 0; j < 4; ++j)
                    vr[j] = *(const float4*)(vp + (kb + j) * DH + db);
            }
        }

        if (act) {
            float p_[4][4];
            __builtin_amdgcn_s_setprio(1);
            #pragma unroll
            for (int kt = 0; kt < 4; ++kt) {
                f32x4 acc = {0.f, 0.f, 0.f, 0.f};
                const int key = kt * 16 + lr;
                #pragma unroll
                for (int s = 0; s < 2; ++s) {
                    const int ki = key * 64 + ((s * 32 + lg * 8) ^ ((key & 7) << 3));
                    const bf16x8 khi = *(const bf16x8*)(&sKhi[ki]);
                    const bf16x8 klo = *(const bf16x8*)(&sKlo[ki]);
                    acc = __builtin_amdgcn_mfma_f32_16x16x32_bf16(khi, qhi[s], acc, 0, 0, 0);
                    acc = __builtin_amdgcn_mfma_f32_16x16x32_bf16(khi, qlo[s], acc, 0, 0, 0);
                    acc = __builtin_amdgcn_mfma_f32_16x16x32_bf16(klo, qhi[s], acc, 0, 0, 0);
                }
                #pragma unroll
                for (int r = 0; r < 4; ++r) p_[kt][r] = acc[r];
            }
            __builtin_amdgcn_s_setprio(0);

            if (kv0 + KVB > n_valid) {
                #pragma unroll
                for (int kt = 0; kt < 4; ++kt) {
                    #pragma unroll
                    for (int r = 0; r < 4; ++r) {
                        if (kv0 + kt * 16 + lg * 4 + r >= n_valid) p_[kt][r] = -1000000.0f;
                    }
                }
            }

            float tm = p_[0][0];
            #pragma unroll
            for (int kt = 0; kt < 4; ++kt) {
                #pragma unroll
                for (int r = 0; r < 4; ++r) tm = fmaxf(tm, p_[kt][r]);
            }
            tm = fmaxf(tm, __shfl_xor(tm, 16));
            tm = fmaxf(tm, __shfl_xor(tm, 32));
            const float mn = fmaxf(m_q, tm);
            const float sc = __expf(m_q - mn);
            float rs = 0.f;
            #pragma unroll
            for (int kt = 0; kt < 4; ++kt) {
                #pragma unroll
                for (int r = 0; r < 4; ++r) {
                    p_[kt][r] = __expf(p_[kt][r] - mn);
                    rs += p_[kt][r];
                }
            }
            rs += __shfl_xor(rs, 16);
            rs += __shfl_xor(rs, 32);
            l_q = l_q * sc + rs;
            m_q = mn;
            #pragma unroll
            for (int r = 0; r < 4; ++r) {
                const float scr = __shfl(sc, lg * 4 + r);
                #pragma unroll
                for (int nt = 0; nt < 4; ++nt) o[nt][r] *= scr;
            }

            #pragma unroll
            for (int s = 0; s < 2; ++s) {
                bf16x8 phi, plo;
                #pragma unroll
                for (int i = 0; i < 8; ++i) {
                    const float v = p_[2 * s + (i >> 2)][i & 3];
                    const unsigned short h = f2bf(v);
                    phi[i] = (short)h;
                    plo[i] = (short)f2bf(v - bf2f(h));
                }
                const int cb = s * 32 + lg * 8;
                __builtin_amdgcn_s_setprio(1);
                #pragma unroll
                for (int nt = 0; nt < 4; ++nt) {
                    const int d  = nt * 16 + lr;
                    const int vi = d * 64 + (cb ^ vswz(d));
                    const bf16x8 vhi = *(const bf16x8*)(&sVhi[vi]);
                    const bf16x8 vlo = *(const bf16x8*)(&sVlo[vi]);
                    o[nt] = __builtin_amdgcn_mfma_f32_16x16x32_bf16(phi, vhi, o[nt], 0, 0, 0);
                    o[nt] = __builtin_amdgcn_mfma_f32_16x16x32_bf16(plo, vhi, o[nt], 0, 0, 0);
                    o[nt] = __builtin_amdgcn_mfma_f32_16x16x32_bf16(phi, vlo, o[nt], 0, 0, 0);
                }
                __builtin_amdgcn_s_setprio(0);
            }
        }
    }

    __syncthreads();
    float* fo = (float*)&sMem[0][0];
    if (wg == 1) {
        #pragma unroll
        for (int nt = 0; nt < 4; ++nt) {
            #pragma unroll
            for (int r = 0; r < 4; ++r)
                fo[(nt * 4 + r) * 256 + w4 * 64 + lane] = o[nt][r];
        }
        if (lg == 0) {
            fo[4096 + w4 * 16 + lr] = m_q;
            fo[4160 + w4 * 16 + lr] = l_q;
        }
    }
    __syncthreads();
    if (wg == 0) {
        const float m1 = fo[4096 + w4 * 16 + lr];
        const float l1 = fo[4160 + w4 * 16 + lr];
        const float mm = fmaxf(m_q, m1);
        const float a0 = __expf(m_q - mm);
        const float a1 = (l1 > 0.f) ? __expf(m1 - mm) : 0.f;
        const float inv = 1.0f / (a0 * l_q + a1 * l1);
        #pragma unroll
        for (int r = 0; r < 4; ++r) {
            const float a0r  = __shfl(a0, lg * 4 + r);
            const float a1r  = __shfl(a1, lg * 4 + r);
            const float invr = __shfl(inv, lg * 4 + r);
            const int row = lg * 4 + r;
            float* op = Og + ((size_t)b * LQS + q0 + w4 * 16 + row) * DH + lr;
            #pragma unroll
            for (int nt = 0; nt < 4; ++nt) {
                const float o1 = fo[(nt * 4 + r) * 256 + w4 * 64 + lane];
                op[nt * 16] = (a0r * o[nt][r] + a1r * o1) * invr;
            }
        }
    }
}

extern "C" void kernel_launch(void* const* d_in, const int* in_sizes, int n_in,
                              void* d_out, int out_size, void* d_ws, size_t ws_size,
                              hipStream_t stream) {
    (void)in_sizes; (void)n_in; (void)out_size;
    const float* Q  = (const float*)d_in[0];
    const float* K  = (const float*)d_in[1];
    const float* V  = (const float*)d_in[2];
    const int*   vl = (const int*)d_in[3];
    float* O = (float*)d_out;

    const size_t oelems = (size_t)NZ * NB * LQS * DH;          // 8,388,608
    const size_t melems = (size_t)NZ * NB * LQS;               // 131,072
    const size_t need   = (oelems + 2 * melems) * sizeof(float);
    if (ws_size >= need) {
        float* Po = (float*)d_ws;
        float* Pm = Po + oelems;
        float* Pl = Pm + melems;
        attn_fa_split<<<dim3(LQS / 128, NB, NZ), 512, 0, stream>>>(Q, K, V, vl, Po, Pm, Pl);
        attn_combine<<<(NB * LQS * DH) / 256, 256, 0, stream>>>(Po, Pm, Pl, O);
    } else {
        attn_fa<<<dim3(LQS / 64, NB), 512, 0, stream>>>(Q, K, V, vl, O);
    }
}